// Round 7
// baseline (2385.587 us; speedup 1.0000x reference)
//
#include <hip/hip_runtime.h>
#include <hip/hip_fp16.h>
#include <math.h>

#define HDIM 2048
#define G4   (4 * HDIM)   // 8192 gate rows
#define NBLK 128          // persistent grid
#define TPB  512          // threads per block (8 waves)
#define NSLOT 1024        // h slots per buffer (2 fp16 per slot)

// __builtin_amdgcn_cvt_pkrtz / __builtin_amdgcn_fdot2 use the __fp16 vector
// type (NOT _Float16 — they don't implicitly convert).
typedef __fp16 h2_t __attribute__((ext_vector_type(2)));

__device__ __forceinline__ float fast_sigmoid(float x) {
    return 1.0f / (1.0f + __expf(-x));
}
__device__ __forceinline__ float fast_tanh(float x) {
    // 1 - 2/(1+e^{2x}): exact saturation at +/-inf, ~1e-6 rel err.
    return 1.0f - 2.0f / (1.0f + __expf(2.0f * x));
}

// ---------------------------------------------------------------------------
// prep: b_sum = b_ih + b_hh ; c = 0 ; tagged h slots = 0 (tag 0 = invalid)
// ---------------------------------------------------------------------------
__global__ __launch_bounds__(256) void prep_small(const float* __restrict__ bih,
                                                  const float* __restrict__ bhh,
                                                  float* __restrict__ bsum,
                                                  float* __restrict__ c,
                                                  unsigned long long* __restrict__ slots) {
    int i = blockIdx.x * blockDim.x + threadIdx.x;
    if (i < G4) bsum[i] = bih[i] + bhh[i];
    if (i < HDIM) c[i] = 0.0f;
    if (i < 2 * NSLOT) slots[i] = 0ull;
}

// ---------------------------------------------------------------------------
// prep: W_sum = fp16(W_ih + W_hh)
// ---------------------------------------------------------------------------
__global__ __launch_bounds__(256) void prep_wsum_h(const float* __restrict__ Wih,
                                                   const float* __restrict__ Whh,
                                                   __half* __restrict__ Wsum) {
    const int n8 = (G4 * HDIM) / 8;
    int idx = blockIdx.x * blockDim.x + threadIdx.x;
    int stride = gridDim.x * blockDim.x;
    const float4* a = (const float4*)Wih;
    const float4* b = (const float4*)Whh;
    for (int i = idx; i < n8; i += stride) {
        float4 a0 = a[2 * i], a1 = a[2 * i + 1];
        float4 b0 = b[2 * i], b1 = b[2 * i + 1];
        __half h[8];
        h[0] = __float2half(a0.x + b0.x);
        h[1] = __float2half(a0.y + b0.y);
        h[2] = __float2half(a0.z + b0.z);
        h[3] = __float2half(a0.w + b0.w);
        h[4] = __float2half(a1.x + b1.x);
        h[5] = __float2half(a1.y + b1.y);
        h[6] = __float2half(a1.z + b1.z);
        h[7] = __float2half(a1.w + b1.w);
        ((uint4*)Wsum)[i] = *(const uint4*)h;
    }
}

// ---------------------------------------------------------------------------
// t=0 step, exact fp32: gates = X @ W_ih.T + bsum (h0 = 0). Writes h->out[0],
// c->c[], and publishes h_0 into slots buf 0 with tag 1. 256 blocks x 256.
// ---------------------------------------------------------------------------
__global__ __launch_bounds__(256) void lstm_step_f32(const float* __restrict__ x,
                                                     const float* __restrict__ W,
                                                     const float* __restrict__ bsum,
                                                     float* __restrict__ c,
                                                     float* __restrict__ h_out,
                                                     unsigned long long* __restrict__ slots) {
    __shared__ float gates[4][8];
    __shared__ float h_sh[8];
    const int tid  = threadIdx.x;
    const int wave = tid >> 6;
    const int lane = tid & 63;
    const int j0   = blockIdx.x * 8;

    float4 xv[8];
    const float4* xp = (const float4*)x;
#pragma unroll
    for (int k = 0; k < 8; ++k) xv[k] = xp[lane + 64 * k];

    float acc[8];
#pragma unroll
    for (int j8 = 0; j8 < 8; ++j8) {
        const int R = wave * HDIM + j0 + j8;
        const float4* wr = (const float4*)(W + (size_t)R * HDIM);
        float a = 0.0f;
#pragma unroll
        for (int k = 0; k < 8; ++k) {
            float4 wv = wr[lane + 64 * k];
            a += wv.x * xv[k].x + wv.y * xv[k].y + wv.z * xv[k].z + wv.w * xv[k].w;
        }
        acc[j8] = a;
    }
#pragma unroll
    for (int j8 = 0; j8 < 8; ++j8) {
        float a = acc[j8];
#pragma unroll
        for (int off = 32; off > 0; off >>= 1) a += __shfl_down(a, off, 64);
        if (lane == 0) gates[wave][j8] = a + bsum[wave * HDIM + j0 + j8];
    }
    __syncthreads();
    if (tid < 8) {
        const int j = j0 + tid;
        const float si = 1.0f / (1.0f + expf(-gates[0][tid]));
        const float so = 1.0f / (1.0f + expf(-gates[3][tid]));
        const float tg = tanhf(gates[2][tid]);
        const float cn = si * tg;  // c0 = 0
        c[j] = cn;
        const float h = so * tanhf(cn);
        h_out[j]  = h;
        h_sh[tid] = h;
    }
    __syncthreads();
    if (tid < 4) {
        h2_t hp;
#if __has_builtin(__builtin_amdgcn_cvt_pkrtz)
        hp = __builtin_amdgcn_cvt_pkrtz(h_sh[2 * tid], h_sh[2 * tid + 1]);
#else
        hp = h2_t{(__fp16)h_sh[2 * tid], (__fp16)h_sh[2 * tid + 1]};
#endif
        unsigned long long pk = (1ull << 32) | (unsigned long long)__builtin_bit_cast(unsigned, hp);
        __hip_atomic_store(&slots[blockIdx.x * 4 + tid], pk,
                           __ATOMIC_RELAXED, __HIP_MEMORY_SCOPE_AGENT);
    }
}

// ---------------------------------------------------------------------------
// Round-2 per-step fp16 kernel — runtime fallback if cooperative launch fails.
// ---------------------------------------------------------------------------
__global__ __launch_bounds__(256) void lstm_step_h(const float* __restrict__ x,
                                                   const __half* __restrict__ W,
                                                   const float* __restrict__ bsum,
                                                   float* __restrict__ c,
                                                   float* __restrict__ h_out) {
    __shared__ float gates[4][8];
    const int tid  = threadIdx.x;
    const int wave = tid >> 6;
    const int lane = tid & 63;
    const int j0   = blockIdx.x * 8;

    float xv[32];
    const float4* xp = (const float4*)x;
#pragma unroll
    for (int k = 0; k < 4; ++k) {
        float4 a = xp[k * 128 + lane * 2];
        float4 b = xp[k * 128 + lane * 2 + 1];
        xv[k * 8 + 0] = a.x; xv[k * 8 + 1] = a.y; xv[k * 8 + 2] = a.z; xv[k * 8 + 3] = a.w;
        xv[k * 8 + 4] = b.x; xv[k * 8 + 5] = b.y; xv[k * 8 + 6] = b.z; xv[k * 8 + 7] = b.w;
    }
    float acc[8];
#pragma unroll
    for (int j8 = 0; j8 < 8; ++j8) {
        const int R = wave * HDIM + j0 + j8;
        const uint4* wr = (const uint4*)(W + (size_t)R * HDIM);
        float a = 0.0f;
#pragma unroll
        for (int k = 0; k < 4; ++k) {
            uint4 wv = wr[k * 64 + lane];
            const __half* hh = (const __half*)&wv;
#pragma unroll
            for (int e = 0; e < 8; ++e)
                a = fmaf(__half2float(hh[e]), xv[k * 8 + e], a);
        }
        acc[j8] = a;
    }
#pragma unroll
    for (int j8 = 0; j8 < 8; ++j8) {
        float a = acc[j8];
#pragma unroll
        for (int off = 32; off > 0; off >>= 1) a += __shfl_down(a, off, 64);
        if (lane == 0) gates[wave][j8] = a + bsum[wave * HDIM + j0 + j8];
    }
    __syncthreads();
    if (tid < 8) {
        const int j = j0 + tid;
        const float si = 1.0f / (1.0f + expf(-gates[0][tid]));
        const float sf = 1.0f / (1.0f + expf(-gates[1][tid]));
        const float so = 1.0f / (1.0f + expf(-gates[3][tid]));
        const float tg = tanhf(gates[2][tid]);
        const float cn = sf * c[j] + si * tg;
        c[j]     = cn;
        h_out[j] = so * tanhf(cn);
    }
}

// ---------------------------------------------------------------------------
// Persistent kernel, steps 1..T-1. 128 blocks x 512 threads (8 waves).
// WAVE-LOCAL GATES: wave w owns h-elements {16b+2w, 16b+2w+1} and computes
// ALL FOUR gates for them (rows g*2048 + jA + q, j8 = g*2+q) — 8 rows/lane,
// 128 weight VGPRs as before. Butterfly (shfl_xor) reduce leaves full row
// sums in EVERY lane -> pointwise is wave-uniform in registers (c replicated
// per-lane), no LDS gates exchange, no second barrier. Lane 0 publishes the
// wave's h-pair immediately (slot b*8+w). lds_x is double-buffered by step
// parity so the single post-poll barrier is the only barrier per step.
// ---------------------------------------------------------------------------
__global__ __launch_bounds__(TPB, 2) void lstm_persist(const __half* __restrict__ W,
                                                       const float* __restrict__ bsum,
                                                       const float* __restrict__ c0,
                                                       float* __restrict__ out,
                                                       unsigned long long* __restrict__ slots,
                                                       int T) {
    const int tid  = threadIdx.x;
    const int wave = tid >> 6;        // 0..7
    const int lane = tid & 63;
    const int j0   = blockIdx.x * 16;
    const int jA   = j0 + 2 * wave;   // this wave's two h indices: jA, jA+1

    // One-time: weights into registers. Row j8 = g*2+q  ->  W[g*2048 + jA+q].
    uint4 w[8][4];
    float bias[8];
#pragma unroll
    for (int g = 0; g < 4; ++g)
#pragma unroll
        for (int q = 0; q < 2; ++q) {
            const int j8 = g * 2 + q;
            const size_t R = (size_t)g * HDIM + jA + q;
            const uint4* wr = (const uint4*)(W + R * HDIM);
#pragma unroll
            for (int e = 0; e < 4; ++e) w[j8][e] = wr[lane + 64 * e];
            bias[j8] = bsum[R];
        }

    // c for the wave's two h, replicated across all 64 lanes.
    float cA = c0[jA];
    float cB = c0[jA + 1];

    __shared__ __align__(16) unsigned lds_x[2][NSLOT];  // double-buffered h pairs

    for (int t = 1; t < T; ++t) {
        const int buf = (t - 1) & 1;
        // ---- dedup poll: wave w owns slots [w*128, w*128+128), 2/lane ----
        const unsigned long long* sl = slots + (size_t)buf * NSLOT;
        const unsigned tg = (unsigned)t;
        const int s0 = wave * 128 + lane;
        const int s1 = s0 + 64;
        unsigned long long v0 = __hip_atomic_load(&sl[s0], __ATOMIC_RELAXED,
                                                  __HIP_MEMORY_SCOPE_AGENT);
        unsigned long long v1 = __hip_atomic_load(&sl[s1], __ATOMIC_RELAXED,
                                                  __HIP_MEMORY_SCOPE_AGENT);
        int spin = 0;
        while (((unsigned)(v0 >> 32) != tg) | ((unsigned)(v1 >> 32) != tg)) {
            if (spin++) __builtin_amdgcn_s_sleep(1);
            if ((unsigned)(v0 >> 32) != tg)
                v0 = __hip_atomic_load(&sl[s0], __ATOMIC_RELAXED,
                                       __HIP_MEMORY_SCOPE_AGENT);
            if ((unsigned)(v1 >> 32) != tg)
                v1 = __hip_atomic_load(&sl[s1], __ATOMIC_RELAXED,
                                       __HIP_MEMORY_SCOPE_AGENT);
        }
        lds_x[buf][s0] = (unsigned)v0;
        lds_x[buf][s1] = (unsigned)v1;
        __syncthreads();  // the ONLY barrier per step

        // ---- dot: 8 rows x 32 cols per lane, x pairs from LDS ----
        float acc[8] = {0.f, 0.f, 0.f, 0.f, 0.f, 0.f, 0.f, 0.f};
#pragma unroll
        for (int e = 0; e < 4; ++e) {
            const uint4 xq = *(const uint4*)&lds_x[buf][(lane + 64 * e) * 4];
            const unsigned xs[4] = {xq.x, xq.y, xq.z, xq.w};
#pragma unroll
            for (int p = 0; p < 4; ++p) {
                const h2_t xh = __builtin_bit_cast(h2_t, xs[p]);
#pragma unroll
                for (int j8 = 0; j8 < 8; ++j8) {
                    const h2_t* wh = (const h2_t*)&w[j8][e];
#if __has_builtin(__builtin_amdgcn_fdot2)
                    acc[j8] = __builtin_amdgcn_fdot2(wh[p], xh, acc[j8], false);
#else
                    acc[j8] = fmaf((float)wh[p][0], (float)xh[0],
                                   fmaf((float)wh[p][1], (float)xh[1], acc[j8]));
#endif
                }
            }
        }

        // ---- butterfly reduce: every lane ends with the full row sums ----
#pragma unroll
        for (int j8 = 0; j8 < 8; ++j8) {
#pragma unroll
            for (int off = 32; off > 0; off >>= 1)
                acc[j8] += __shfl_xor(acc[j8], off, 64);
        }

        // ---- wave-uniform pointwise in registers (rows: j8 = g*2+q) ----
        const float iA = fast_sigmoid(acc[0] + bias[0]);
        const float iB = fast_sigmoid(acc[1] + bias[1]);
        const float fA = fast_sigmoid(acc[2] + bias[2]);
        const float fB = fast_sigmoid(acc[3] + bias[3]);
        const float gA = fast_tanh(acc[4] + bias[4]);
        const float gB = fast_tanh(acc[5] + bias[5]);
        const float oA = fast_sigmoid(acc[6] + bias[6]);
        const float oB = fast_sigmoid(acc[7] + bias[7]);
        cA = fA * cA + iA * gA;
        cB = fB * cB + iB * gB;
        const float hA = oA * fast_tanh(cA);
        const float hB = oB * fast_tanh(cB);

        // ---- publish h-pair (slot b*8+w, buf t&1, tag t+1), then out[] ----
        if (lane == 0) {
            h2_t hp;
#if __has_builtin(__builtin_amdgcn_cvt_pkrtz)
            hp = __builtin_amdgcn_cvt_pkrtz(hA, hB);
#else
            hp = h2_t{(__fp16)hA, (__fp16)hB};
#endif
            unsigned long long pk = ((unsigned long long)(unsigned)(t + 1) << 32)
                                  | (unsigned long long)__builtin_bit_cast(unsigned, hp);
            __hip_atomic_store(&slots[(size_t)(t & 1) * NSLOT + blockIdx.x * 8 + wave], pk,
                               __ATOMIC_RELAXED, __HIP_MEMORY_SCOPE_AGENT);
            *(float2*)&out[(size_t)t * HDIM + jA] = make_float2(hA, hB);
        }
    }
}

// ---------------------------------------------------------------------------
extern "C" void kernel_launch(void* const* d_in, const int* in_sizes, int n_in,
                              void* d_out, int out_size, void* d_ws, size_t ws_size,
                              hipStream_t stream) {
    const float* X   = (const float*)d_in[0];
    const float* Wih = (const float*)d_in[1];
    const float* Whh = (const float*)d_in[2];
    const float* bih = (const float*)d_in[3];
    const float* bhh = (const float*)d_in[4];
    float* out = (float*)d_out;

    int T = out_size / HDIM;  // 512

    // ws: [W_sum fp16 33.55 MB][b_sum 32 KB][c 8 KB][slots 16 KB]
    const size_t wsum_bytes = (size_t)G4 * HDIM * sizeof(__half);
    char* ws = (char*)d_ws;
    __half* Wsum = (__half*)ws;
    float*  bsum = (float*)(ws + wsum_bytes);
    float*  c    = bsum + G4;
    unsigned long long* slots = (unsigned long long*)(c + HDIM);

    prep_small<<<(G4 + 255) / 256, 256, 0, stream>>>(bih, bhh, bsum, c, slots);
    prep_wsum_h<<<2048, 256, 0, stream>>>(Wih, Whh, Wsum);

    // t = 0: exact fp32, publishes h_0 into slots (buf 0, tag 1).
    lstm_step_f32<<<256, 256, 0, stream>>>(X, Wih, bsum, c, out, slots);

    // t >= 1: persistent kernel, wave-local gates, fence-free dataflow.
    void* args[] = {(void*)&Wsum, (void*)&bsum, (void*)&c, (void*)&out,
                    (void*)&slots, (void*)&T};
    hipError_t err = hipLaunchCooperativeKernel((const void*)lstm_persist,
                                                dim3(NBLK), dim3(TPB), args, 0, stream);
    if (err != hipSuccess) {
        // Fallback: proven round-2 per-step loop.
        for (int t = 1; t < T; ++t) {
            const float* hprev = out + (size_t)(t - 1) * HDIM;
            float* hnext = out + (size_t)t * HDIM;
            lstm_step_h<<<256, 256, 0, stream>>>(hprev, Wsum, bsum, c, hnext);
        }
    }
}

// Round 8
// 1771.012 us; speedup vs baseline: 1.3470x; 1.3470x over previous
//
#include <hip/hip_runtime.h>
#include <hip/hip_fp16.h>
#include <math.h>

#define HDIM 2048
#define G4   (4 * HDIM)   // 8192 gate rows
#define NBLK 128          // persistent grid
#define TPB  512          // threads per block (8 waves)
#define NSLOT 1024        // h slots per buffer (2 fp16 per slot)

// __builtin_amdgcn_cvt_pkrtz / __builtin_amdgcn_fdot2 use the __fp16 vector
// type (NOT _Float16 — they don't implicitly convert).
typedef __fp16 h2_t __attribute__((ext_vector_type(2)));

__device__ __forceinline__ float fast_sigmoid(float x) {
    return 1.0f / (1.0f + __expf(-x));
}
__device__ __forceinline__ float fast_tanh(float x) {
    return 1.0f - 2.0f / (1.0f + __expf(2.0f * x));
}
__device__ __forceinline__ h2_t pk2(float a, float b) {
#if __has_builtin(__builtin_amdgcn_cvt_pkrtz)
    return __builtin_amdgcn_cvt_pkrtz(a, b);
#else
    return h2_t{(__fp16)a, (__fp16)b};
#endif
}

// ---------------------------------------------------------------------------
// prep: zero the tagged slot buffers (tag 0 = invalid). 8 x 256 covers 2048.
// ---------------------------------------------------------------------------
__global__ __launch_bounds__(256) void prep_slots(unsigned long long* __restrict__ slots) {
    int i = blockIdx.x * blockDim.x + threadIdx.x;
    if (i < 2 * NSLOT) slots[i] = 0ull;
}

// ---------------------------------------------------------------------------
// Fallback-path kernels (round-2 proven pipeline), used only if the
// cooperative launch is rejected.
// ---------------------------------------------------------------------------
__global__ __launch_bounds__(256) void prep_small(const float* __restrict__ bih,
                                                  const float* __restrict__ bhh,
                                                  float* __restrict__ bsum,
                                                  float* __restrict__ c) {
    int i = blockIdx.x * blockDim.x + threadIdx.x;
    if (i < G4) bsum[i] = bih[i] + bhh[i];
    if (i < HDIM) c[i] = 0.0f;
}

__global__ __launch_bounds__(256) void prep_wsum_h(const float* __restrict__ Wih,
                                                   const float* __restrict__ Whh,
                                                   __half* __restrict__ Wsum) {
    const int n8 = (G4 * HDIM) / 8;
    int idx = blockIdx.x * blockDim.x + threadIdx.x;
    int stride = gridDim.x * blockDim.x;
    const float4* a = (const float4*)Wih;
    const float4* b = (const float4*)Whh;
    for (int i = idx; i < n8; i += stride) {
        float4 a0 = a[2 * i], a1 = a[2 * i + 1];
        float4 b0 = b[2 * i], b1 = b[2 * i + 1];
        __half h[8];
        h[0] = __float2half(a0.x + b0.x);
        h[1] = __float2half(a0.y + b0.y);
        h[2] = __float2half(a0.z + b0.z);
        h[3] = __float2half(a0.w + b0.w);
        h[4] = __float2half(a1.x + b1.x);
        h[5] = __float2half(a1.y + b1.y);
        h[6] = __float2half(a1.z + b1.z);
        h[7] = __float2half(a1.w + b1.w);
        ((uint4*)Wsum)[i] = *(const uint4*)h;
    }
}

__global__ __launch_bounds__(256) void lstm_step_f32(const float* __restrict__ x,
                                                     const float* __restrict__ W,
                                                     const float* __restrict__ bsum,
                                                     float* __restrict__ c,
                                                     float* __restrict__ h_out) {
    __shared__ float gates[4][8];
    const int tid  = threadIdx.x;
    const int wave = tid >> 6;
    const int lane = tid & 63;
    const int j0   = blockIdx.x * 8;

    float4 xv[8];
    const float4* xp = (const float4*)x;
#pragma unroll
    for (int k = 0; k < 8; ++k) xv[k] = xp[lane + 64 * k];

    float acc[8];
#pragma unroll
    for (int j8 = 0; j8 < 8; ++j8) {
        const int R = wave * HDIM + j0 + j8;
        const float4* wr = (const float4*)(W + (size_t)R * HDIM);
        float a = 0.0f;
#pragma unroll
        for (int k = 0; k < 8; ++k) {
            float4 wv = wr[lane + 64 * k];
            a += wv.x * xv[k].x + wv.y * xv[k].y + wv.z * xv[k].z + wv.w * xv[k].w;
        }
        acc[j8] = a;
    }
#pragma unroll
    for (int j8 = 0; j8 < 8; ++j8) {
        float a = acc[j8];
#pragma unroll
        for (int off = 32; off > 0; off >>= 1) a += __shfl_down(a, off, 64);
        if (lane == 0) gates[wave][j8] = a + bsum[wave * HDIM + j0 + j8];
    }
    __syncthreads();
    if (tid < 8) {
        const int j = j0 + tid;
        const float si = 1.0f / (1.0f + expf(-gates[0][tid]));
        const float so = 1.0f / (1.0f + expf(-gates[3][tid]));
        const float tg = tanhf(gates[2][tid]);
        const float cn = si * tg;  // c0 = 0
        c[j]     = cn;
        h_out[j] = so * tanhf(cn);
    }
}

__global__ __launch_bounds__(256) void lstm_step_h(const float* __restrict__ x,
                                                   const __half* __restrict__ W,
                                                   const float* __restrict__ bsum,
                                                   float* __restrict__ c,
                                                   float* __restrict__ h_out) {
    __shared__ float gates[4][8];
    const int tid  = threadIdx.x;
    const int wave = tid >> 6;
    const int lane = tid & 63;
    const int j0   = blockIdx.x * 8;

    float xv[32];
    const float4* xp = (const float4*)x;
#pragma unroll
    for (int k = 0; k < 4; ++k) {
        float4 a = xp[k * 128 + lane * 2];
        float4 b = xp[k * 128 + lane * 2 + 1];
        xv[k * 8 + 0] = a.x; xv[k * 8 + 1] = a.y; xv[k * 8 + 2] = a.z; xv[k * 8 + 3] = a.w;
        xv[k * 8 + 4] = b.x; xv[k * 8 + 5] = b.y; xv[k * 8 + 6] = b.z; xv[k * 8 + 7] = b.w;
    }
    float acc[8];
#pragma unroll
    for (int j8 = 0; j8 < 8; ++j8) {
        const int R = wave * HDIM + j0 + j8;
        const uint4* wr = (const uint4*)(W + (size_t)R * HDIM);
        float a = 0.0f;
#pragma unroll
        for (int k = 0; k < 4; ++k) {
            uint4 wv = wr[k * 64 + lane];
            const __half* hh = (const __half*)&wv;
#pragma unroll
            for (int e = 0; e < 8; ++e)
                a = fmaf(__half2float(hh[e]), xv[k * 8 + e], a);
        }
        acc[j8] = a;
    }
#pragma unroll
    for (int j8 = 0; j8 < 8; ++j8) {
        float a = acc[j8];
#pragma unroll
        for (int off = 32; off > 0; off >>= 1) a += __shfl_down(a, off, 64);
        if (lane == 0) gates[wave][j8] = a + bsum[wave * HDIM + j0 + j8];
    }
    __syncthreads();
    if (tid < 8) {
        const int j = j0 + tid;
        const float si = 1.0f / (1.0f + expf(-gates[0][tid]));
        const float sf = 1.0f / (1.0f + expf(-gates[1][tid]));
        const float so = 1.0f / (1.0f + expf(-gates[3][tid]));
        const float tg = tanhf(gates[2][tid]);
        const float cn = sf * c[j] + si * tg;
        c[j]     = cn;
        h_out[j] = so * tanhf(cn);
    }
}

// ---------------------------------------------------------------------------
// Self-contained persistent kernel: does EVERYTHING (weight convert, step 0,
// steps 1..T-1). 128 blocks x 512 threads. Wave w owns h {16b+2w, 16b+2w+1}
// and all 4 gates for them (8 rows, 128 fp16-weight VGPRs/lane).
//
// Prologue (once): each lane streams its 32 columns of its 8 fp32 rows of
// W_ih and W_hh, packs W_sum=fp16(Wih+Whh) into registers, and accumulates
// step-0's X@W_ih.T dot IN THE SAME PASS (rows already in flight).
//
// Per step: dedup poll (wave-owned 128 slots, 2 x 8-B atomic loads/lane) ->
// LDS -> barrier -> fdot2 dot -> butterfly reduce (all lanes get row sums)
// -> wave-uniform fast pointwise -> lane0 drops h-pair in LDS + writes out[]
// (scattered, off critical path) -> barrier -> wave 0 publishes the block's
// 8 slots as ONE contiguous 64-B burst (r7 showed scattered 8-B slot stores
// cause TCC sector-RMW churn: +40 MB FETCH, slower visibility).
// ---------------------------------------------------------------------------
__global__ __launch_bounds__(TPB, 2) void lstm_persist(const float* __restrict__ X,
                                                       const float* __restrict__ Wih,
                                                       const float* __restrict__ Whh,
                                                       const float* __restrict__ bih,
                                                       const float* __restrict__ bhh,
                                                       float* __restrict__ out,
                                                       unsigned long long* __restrict__ slots,
                                                       int T) {
    const int tid  = threadIdx.x;
    const int wave = tid >> 6;        // 0..7
    const int lane = tid & 63;
    const int jA   = blockIdx.x * 16 + 2 * wave;  // wave's h indices jA, jA+1

    if (wave == 0) __builtin_amdgcn_s_setprio(1);  // publisher wave priority

    // ---- X columns for this lane (e-major, matches weight layout) ----
    float xv[32];
    {
        const float4* xp = (const float4*)X;
#pragma unroll
        for (int e = 0; e < 4; ++e) {
            float4 a = xp[(lane + 64 * e) * 2];
            float4 b = xp[(lane + 64 * e) * 2 + 1];
            xv[e * 8 + 0] = a.x; xv[e * 8 + 1] = a.y; xv[e * 8 + 2] = a.z; xv[e * 8 + 3] = a.w;
            xv[e * 8 + 4] = b.x; xv[e * 8 + 5] = b.y; xv[e * 8 + 6] = b.z; xv[e * 8 + 7] = b.w;
        }
    }

    // ---- weight convert + step-0 dot, fused ----
    uint4 w[8][4];
    float bias[8], acc[8];
#pragma unroll
    for (int g = 0; g < 4; ++g)
#pragma unroll
        for (int q = 0; q < 2; ++q) {
            const int j8 = g * 2 + q;
            const size_t R = (size_t)g * HDIM + jA + q;
            const float4* ri = (const float4*)(Wih + R * HDIM);
            const float4* rh = (const float4*)(Whh + R * HDIM);
            float a0acc = 0.0f;
#pragma unroll
            for (int e = 0; e < 4; ++e) {
                float4 a0 = ri[(lane + 64 * e) * 2];
                float4 a1 = ri[(lane + 64 * e) * 2 + 1];
                float4 b0 = rh[(lane + 64 * e) * 2];
                float4 b1 = rh[(lane + 64 * e) * 2 + 1];
                a0acc += a0.x * xv[e * 8 + 0] + a0.y * xv[e * 8 + 1]
                       + a0.z * xv[e * 8 + 2] + a0.w * xv[e * 8 + 3]
                       + a1.x * xv[e * 8 + 4] + a1.y * xv[e * 8 + 5]
                       + a1.z * xv[e * 8 + 6] + a1.w * xv[e * 8 + 7];
                h2_t p0 = pk2(a0.x + b0.x, a0.y + b0.y);
                h2_t p1 = pk2(a0.z + b0.z, a0.w + b0.w);
                h2_t p2 = pk2(a1.x + b1.x, a1.y + b1.y);
                h2_t p3 = pk2(a1.z + b1.z, a1.w + b1.w);
                w[j8][e] = make_uint4(__builtin_bit_cast(unsigned, p0),
                                      __builtin_bit_cast(unsigned, p1),
                                      __builtin_bit_cast(unsigned, p2),
                                      __builtin_bit_cast(unsigned, p3));
            }
            acc[j8]  = a0acc;
            bias[j8] = bih[R] + bhh[R];
        }

    __shared__ __align__(16) unsigned lds_x[2][NSLOT];  // double-buffered h pairs
    __shared__ unsigned h_pack[8];                      // per-wave packed h2

    float cA = 0.0f, cB = 0.0f;

    // ---- step 0: butterfly + pointwise (c0 = 0) + publish tag 1, buf 0 ----
#pragma unroll
    for (int j8 = 0; j8 < 8; ++j8)
#pragma unroll
        for (int off = 32; off > 0; off >>= 1)
            acc[j8] += __shfl_xor(acc[j8], off, 64);
    {
        const float iA = fast_sigmoid(acc[0] + bias[0]);
        const float iB = fast_sigmoid(acc[1] + bias[1]);
        const float gA = fast_tanh(acc[4] + bias[4]);
        const float gB = fast_tanh(acc[5] + bias[5]);
        const float oA = fast_sigmoid(acc[6] + bias[6]);
        const float oB = fast_sigmoid(acc[7] + bias[7]);
        cA = iA * gA;
        cB = iB * gB;
        const float hA = oA * fast_tanh(cA);
        const float hB = oB * fast_tanh(cB);
        if (lane == 0) {
            h_pack[wave] = __builtin_bit_cast(unsigned, pk2(hA, hB));
            *(float2*)&out[jA] = make_float2(hA, hB);
        }
    }
    __syncthreads();
    if (wave == 0 && lane < 8) {
        unsigned long long pkv = (1ull << 32) | (unsigned long long)h_pack[lane];
        __hip_atomic_store(&slots[blockIdx.x * 8 + lane], pkv,
                           __ATOMIC_RELAXED, __HIP_MEMORY_SCOPE_AGENT);
    }

    // ---- steps 1..T-1 ----
    for (int t = 1; t < T; ++t) {
        const int buf = (t - 1) & 1;
        const unsigned long long* sl = slots + (size_t)buf * NSLOT;
        const unsigned tg = (unsigned)t;
        const int s0 = wave * 128 + lane;
        const int s1 = s0 + 64;
        unsigned long long v0 = __hip_atomic_load(&sl[s0], __ATOMIC_RELAXED,
                                                  __HIP_MEMORY_SCOPE_AGENT);
        unsigned long long v1 = __hip_atomic_load(&sl[s1], __ATOMIC_RELAXED,
                                                  __HIP_MEMORY_SCOPE_AGENT);
        int spin = 0;
        while (((unsigned)(v0 >> 32) != tg) | ((unsigned)(v1 >> 32) != tg)) {
            if (spin++) __builtin_amdgcn_s_sleep(1);
            if ((unsigned)(v0 >> 32) != tg)
                v0 = __hip_atomic_load(&sl[s0], __ATOMIC_RELAXED,
                                       __HIP_MEMORY_SCOPE_AGENT);
            if ((unsigned)(v1 >> 32) != tg)
                v1 = __hip_atomic_load(&sl[s1], __ATOMIC_RELAXED,
                                       __HIP_MEMORY_SCOPE_AGENT);
        }
        lds_x[buf][s0] = (unsigned)v0;
        lds_x[buf][s1] = (unsigned)v1;
        __syncthreads();

        // dot: 8 rows x 32 cols per lane
        float a2[8] = {0.f, 0.f, 0.f, 0.f, 0.f, 0.f, 0.f, 0.f};
#pragma unroll
        for (int e = 0; e < 4; ++e) {
            const uint4 xq = *(const uint4*)&lds_x[buf][(lane + 64 * e) * 4];
            const unsigned xs[4] = {xq.x, xq.y, xq.z, xq.w};
#pragma unroll
            for (int p = 0; p < 4; ++p) {
                const h2_t xh = __builtin_bit_cast(h2_t, xs[p]);
#pragma unroll
                for (int j8 = 0; j8 < 8; ++j8) {
                    const h2_t* wh = (const h2_t*)&w[j8][e];
#if __has_builtin(__builtin_amdgcn_fdot2)
                    a2[j8] = __builtin_amdgcn_fdot2(wh[p], xh, a2[j8], false);
#else
                    a2[j8] = fmaf((float)wh[p][0], (float)xh[0],
                                  fmaf((float)wh[p][1], (float)xh[1], a2[j8]));
#endif
                }
            }
        }

        // butterfly reduce: every lane ends with all 8 row sums
#pragma unroll
        for (int j8 = 0; j8 < 8; ++j8)
#pragma unroll
            for (int off = 32; off > 0; off >>= 1)
                a2[j8] += __shfl_xor(a2[j8], off, 64);

        // wave-uniform pointwise
        const float iA = fast_sigmoid(a2[0] + bias[0]);
        const float iB = fast_sigmoid(a2[1] + bias[1]);
        const float fA = fast_sigmoid(a2[2] + bias[2]);
        const float fB = fast_sigmoid(a2[3] + bias[3]);
        const float gA = fast_tanh(a2[4] + bias[4]);
        const float gB = fast_tanh(a2[5] + bias[5]);
        const float oA = fast_sigmoid(a2[6] + bias[6]);
        const float oB = fast_sigmoid(a2[7] + bias[7]);
        cA = fA * cA + iA * gA;
        cB = fB * cB + iB * gB;
        const float hA = oA * fast_tanh(cA);
        const float hB = oB * fast_tanh(cB);

        if (lane == 0) {
            h_pack[wave] = __builtin_bit_cast(unsigned, pk2(hA, hB));
            // scattered 8-B stream write: NOT polled, off the critical path
            *(float2*)&out[(size_t)t * HDIM + jA] = make_float2(hA, hB);
        }
        __syncthreads();

        // single-wave contiguous 64-B publish (tag t+1, buf t&1)
        if (wave == 0 && lane < 8) {
            unsigned long long pkv = ((unsigned long long)(unsigned)(t + 1) << 32)
                                   | (unsigned long long)h_pack[lane];
            __hip_atomic_store(&slots[(size_t)(t & 1) * NSLOT + blockIdx.x * 8 + lane],
                               pkv, __ATOMIC_RELAXED, __HIP_MEMORY_SCOPE_AGENT);
        }
    }
}

// ---------------------------------------------------------------------------
extern "C" void kernel_launch(void* const* d_in, const int* in_sizes, int n_in,
                              void* d_out, int out_size, void* d_ws, size_t ws_size,
                              hipStream_t stream) {
    const float* X   = (const float*)d_in[0];
    const float* Wih = (const float*)d_in[1];
    const float* Whh = (const float*)d_in[2];
    const float* bih = (const float*)d_in[3];
    const float* bhh = (const float*)d_in[4];
    float* out = (float*)d_out;

    int T = out_size / HDIM;  // 512

    // ws layout (shared with fallback): [Wsum fp16 33.55MB][bsum][c][slots]
    const size_t wsum_bytes = (size_t)G4 * HDIM * sizeof(__half);
    char* ws = (char*)d_ws;
    __half* Wsum = (__half*)ws;
    float*  bsum = (float*)(ws + wsum_bytes);
    float*  c    = bsum + G4;
    unsigned long long* slots = (unsigned long long*)(c + HDIM);

    prep_slots<<<8, 256, 0, stream>>>(slots);

    // Single self-contained persistent kernel (weight convert + all T steps).
    void* args[] = {(void*)&X, (void*)&Wih, (void*)&Whh, (void*)&bih,
                    (void*)&bhh, (void*)&out, (void*)&slots, (void*)&T};
    hipError_t err = hipLaunchCooperativeKernel((const void*)lstm_persist,
                                                dim3(NBLK), dim3(TPB), args, 0, stream);
    if (err != hipSuccess) {
        // Fallback: proven round-2 pipeline.
        prep_small<<<(G4 + 255) / 256, 256, 0, stream>>>(bih, bhh, bsum, c);
        prep_wsum_h<<<2048, 256, 0, stream>>>(Wih, Whh, Wsum);
        lstm_step_f32<<<256, 256, 0, stream>>>(X, Wih, bsum, c, out);
        for (int t = 1; t < T; ++t) {
            const float* hprev = out + (size_t)(t - 1) * HDIM;
            float* hnext = out + (size_t)t * HDIM;
            lstm_step_h<<<256, 256, 0, stream>>>(hprev, Wsum, bsum, c, hnext);
        }
    }
}